// Round 14
// baseline (161.302 us; speedup 1.0000x reference)
//
#include <hip/hip_runtime.h>
#include <cmath>

#define TPB 256
typedef float floatx4 __attribute__((ext_vector_type(4)));
typedef __bf16 bf16x8 __attribute__((ext_vector_type(8)));
typedef unsigned short ushort8 __attribute__((ext_vector_type(8)));
typedef unsigned int uintx4 __attribute__((ext_vector_type(4)));
typedef unsigned short ushort_t;

// ---------- workspace layout (float units) ----------
#define OFF_PMN 16
#define OFF_PMX 96
#define OFF_B1 520       // 20  f32  (pre-divided by S_N1)
#define OFF_B2 544       // 50  f32  (pre-divided by S_N2)
#define OFF_B3 600       // 500 f32  (pre-divided by S_N3)
#define W1BF_BYTE 6144       // [32][32] u16 int weights (conv1), pair-slot packed (TAPOF)
#define W2BF_BYTE 8192       // [20 chunks][64 co][32 k] u16 int weights (conv2), 81920 B
#define W3BF_BYTE 131072     // w3t: [nt32][c25][ln16][k32] u16 (fc1), 819200 B
#define Q2_BYTE  29360128ULL // q2t: [B/16][c25][ln16][k32] bf16 (6.6 MB)

#define S_X1 (3.5f/255.0f)
#define ZP_X1 36.0f
#define S_N1 (6.0f/255.0f)
#define S_N2 (8.0f/255.0f)
#define S_N3 (10.0f/255.0f)

// LDS pixel stride 24 u16 (R13-verified): 16-lane b128 group -> 2-way bank alias (free).
#define XSTR 24

// conv1 K-slot -> tap map (pair packing). Slot k (0..31): quad=k>>3, j=k&7.
// Each quad's 8 slots = 4 row-adjacent PAIRS readable as one aligned u32 from ximp.
// -1 slots carry zero weight (their A-value is a real-but-ignored neighboring pixel).
__device__ const signed char TAPOF[32] = {
     0,  1,  2,  3,  4, -1,  5,  6,     // quad0: (0,0..4),(0,5)g,(1,0),(1,1)
     7,  8,  9, -1, 10, 11, 12, 13,     // quad1: (1,2..4),(1,5)g,(2,0..3)
    14, -1, 15, 16, 17, 18, 19, -1,     // quad2: (2,4),(2,5)g,(3,0..4),(3,5)g
    20, 21, 22, 23, 24, -1, -1, -1      // quad3: (4,0..4),(4,5)g,g,g
};
// pair-index read offsets per quad (pixel index of each pair's low element)
__device__ const int OFFP[4][4] = {
    {0, 2, 4, 28},          // (0,0),(0,2),(0,4),(1,0)
    {30, 32, 56, 58},       // (1,2),(1,4),(2,0),(2,2)
    {60, 84, 86, 88},       // (2,4),(3,0),(3,2),(3,4)
    {112, 114, 116, 112}    // (4,0),(4,2),(4,4),dup(zero wt)
};

__device__ inline float qclip(float x, float s, float zp){
    return rintf(fminf(fmaxf(zp + x / s, 0.0f), 255.0f));
}
// exact bf16 bits for integer-valued floats |v| < 256
__device__ inline ushort_t bfbits(float v){
    return (ushort_t)(__float_as_uint(v) >> 16);
}

// per-block min/max partials; block->tensor map: 0:c1w 1:c1b 2-5:c2w 6:c2b 7-70:f1w 71:f1b
__global__ __launch_bounds__(TPB) void k_minmax(
        const float* c1w, const float* c1b, const float* c2w, const float* c2b,
        const float* f1w, const float* f1b, float* pmn, float* pmx){
    __shared__ float smn[TPB], smx[TPB];
    int bb = blockIdx.x, tid = threadIdx.x;
    const float* src; int n, sub, nsub;
    if      (bb == 0){ src=c1w; n=500;    sub=0;     nsub=1;  }
    else if (bb == 1){ src=c1b; n=20;     sub=0;     nsub=1;  }
    else if (bb <  6){ src=c2w; n=25000;  sub=bb-2;  nsub=4;  }
    else if (bb == 6){ src=c2b; n=50;     sub=0;     nsub=1;  }
    else if (bb < 71){ src=f1w; n=400000; sub=bb-7;  nsub=64; }
    else             { src=f1b; n=500;    sub=0;     nsub=1;  }
    float mn = INFINITY, mx = -INFINITY;
    for (int i = sub*TPB + tid; i < n; i += nsub*TPB){
        float v = src[i]; mn = fminf(mn, v); mx = fmaxf(mx, v);
    }
    smn[tid] = mn; smx[tid] = mx; __syncthreads();
    for (int s = TPB/2; s > 0; s >>= 1){
        if (tid < s){
            smn[tid] = fminf(smn[tid], smn[tid+s]);
            smx[tid] = fmaxf(smx[tid], smx[tid+s]);
        }
        __syncthreads();
    }
    if (tid == 0){ pmn[bb] = smn[0]; pmx[bb] = smx[0]; }
}

// w2bt chunk packing (20 chunks of K=32):
//   main c in 0..12:   oct q -> tap = 2c + (q>>1), ci = (q&1)*8 + jj   (tap 25 -> zero)
//   residue c in 13..19: oct q -> tap = 4(c-13) + q, ci = 16 + jj (jj<4; jj>=4 -> zero)
#define N_EFF 452157
__global__ __launch_bounds__(TPB) void k_make_eff(
        const float* c1w, const float* c1b, const float* c2w, const float* c2b,
        const float* f1w, const float* f1b, const float* pmn, const float* pmx,
        float* ws, ushort_t* w1bf, ushort_t* w2bf, ushort_t* w3bf){
    __shared__ float sS[6], sZ[6];
    int tid = threadIdx.x;
    int wv = tid >> 6, lane = tid & 63;
    const int starts[6] = {0,1,2,6,7,71};
    const int counts[6] = {1,1,4,1,64,1};
    #pragma unroll
    for (int rep = 0; rep < 2; ++rep){
        int t = wv + rep*4;
        if (t < 6){
            float mn = INFINITY, mx = -INFINITY;
            if (lane < counts[t]){ mn = pmn[starts[t]+lane]; mx = pmx[starts[t]+lane]; }
            #pragma unroll
            for (int off = 32; off > 0; off >>= 1){
                mn = fminf(mn, __shfl_xor(mn, off));
                mx = fmaxf(mx, __shfl_xor(mx, off));
            }
            if (lane == 0){
                float s = (mx - mn) / 255.0f;
                sS[t] = s;
                sZ[t] = truncf(fminf(fmaxf(0.0f - mn / s, 0.0f), 255.0f));
            }
        }
    }
    __syncthreads();

    int i = blockIdx.x * TPB + tid;
    if (i >= N_EFF) return;
    if (i < 1024){                   // w1bf: [n(32)][k(32)] pair-slot packed per TAPOF
        int n = i >> 5, k = i & 31;
        int tap = (int)TAPOF[k];
        float v = 0.0f;
        if (n < 20 && tap >= 0) v = qclip(c1w[n*25 + tap], sS[0], sZ[0]) - sZ[0];
        w1bf[i] = bfbits(v);
    } else if (i < 1044){            // b1 pre-divided by S_N1
        int j = i - 1024;
        ws[OFF_B1 + j] = (sS[1] * (qclip(c1b[j], sS[1], sZ[1]) + sZ[1])) / S_N1;
    } else if (i < 42004){           // w2bt chunk-packed
        int j = i - 1044;
        int c = j >> 11, r = j & 2047, co = r >> 5, k = r & 31;
        int q = k >> 3, jj = k & 7;
        int tap, ci; bool valid;
        if (c < 13){ tap = 2*c + (q>>1); ci = (q&1)*8 + jj; valid = (tap < 25); }
        else       { tap = 4*(c-13) + q; ci = 16 + jj;      valid = (tap < 25) && (jj < 4); }
        valid = valid && (co < 50);
        float v = 0.0f;
        if (valid) v = qclip(c2w[(co*20 + ci)*25 + tap], sS[2], sZ[2]) - sZ[2];
        w2bf[j] = bfbits(v);
    } else if (i < 42054){           // b2 pre-divided by S_N2
        int j = i - 42004;
        ws[OFF_B2 + j] = (sS[3] * (qclip(c2b[j], sS[3], sZ[3]) + sZ[3])) / S_N2;
    } else if (i < 451654){          // w3t: tiled [nt(32)][c(25)][ln(16)][k(32)]
        int j = i - 42054;
        int n = j / 800, k = j - 800*n;
        float v = 0.0f;
        if (n < 500) v = qclip(f1w[n*800 + k], sS[4], sZ[4]) - sZ[4];
        w3bf[(((n>>4)*25 + (k>>5))*16 + (n&15))*32 + (k&31)] = bfbits(v);
    } else if (i < 452154){          // b3 pre-divided by S_N3
        int j = i - 451654;
        ws[OFF_B3 + j] = (sS[5] * (qclip(f1b[j], sS[5], sZ[5]) + sZ[5])) / S_N3;
    } else if (i == 452154){
        ws[0] = (S_N1 * sS[2]) / S_N2;   // conv2 combined scale, pre-divided
    } else if (i == 452155){
        ws[1] = (S_N2 * sS[4]) / S_N3;   // fc1 combined scale, pre-divided
    } else {
        ws[2] = (S_X1 * sS[0]) / S_N1;   // conv1 combined scale, pre-divided
    }
}

// Fused conv1+conv2, TWO images per block (grid B/2).
// R26: conv2 wave mapping 2mt x 2nt -> 1mt x 4nt. Halves conv2's LDS A-reads (the
// binding resource: dur invariant to occupancy 70%->33% while VALU 34%/MFMA 23%/HBM 4%
// -> LDS unit ~75% busy by cycle audit). Pays 2x conv2 B VMEM instrs (L1-resident 4KB
// per c-chunk). Coverage: wave w owns (mt=w, nt=0..3); epilogue shfl partners share
// (mt,ni,co). Math bit-identical.
__global__ __launch_bounds__(TPB, 4) void k_conv12(const float* x, const ushort_t* w1bf,
                                                   const ushort_t* w2bt, const float* ws,
                                                   ushort_t* q2bf, int B){
    __shared__ __align__(16) ushort_t xs[2][144*XSTR];    // conv2 input per image
    __shared__ __align__(16) unsigned int ximp[2][784];   // pair-packed quantized images
    int b0 = blockIdx.x * 2, tid = threadIdx.x;
    int lane = tid & 63, wv = tid >> 6;
    int ln = lane & 15, quad = lane >> 4;

    // zero xs pad columns 20-23 once
    for (int i = tid; i < 288; i += TPB){
        int img = i >= 144 ? 1 : 0;
        int p = i - img*144;
        *(unsigned int*)(xs[img] + p*XSTR + 20) = 0u;
        *(unsigned int*)(xs[img] + p*XSTR + 22) = 0u;
    }

    // ---------------- conv1 phase ----------------
    #pragma unroll
    for (int img = 0; img < 2; ++img){
        const float* xb = x + (size_t)(b0 + img) * 784;
        if (tid < 196){
            floatx4 v = *(const floatx4*)(xb + tid*4);
            float x5 = (tid < 195) ? xb[tid*4 + 4] : 0.0f;
            ushort_t bq[5];
            #pragma unroll
            for (int j = 0; j < 4; ++j)
                bq[j] = bfbits(rintf(fminf(fmaxf(ZP_X1 + v[j] / S_X1, 0.0f), 255.0f)) - ZP_X1);
            bq[4] = bfbits(rintf(fminf(fmaxf(ZP_X1 + x5 / S_X1, 0.0f), 255.0f)) - ZP_X1);
            uintx4 P;
            #pragma unroll
            for (int j = 0; j < 4; ++j)
                P[j] = (unsigned int)bq[j] | ((unsigned int)bq[j+1] << 16);
            *(uintx4*)(&ximp[img][tid*4]) = P;
        }
    }

    int o0 = OFFP[quad][0], o1 = OFFP[quad][1], o2 = OFFP[quad][2], o3 = OFFP[quad][3];

    ushort8 bw0 = *(const ushort8*)(w1bf + ln*32 + quad*8);
    ushort8 bw1 = *(const ushort8*)(w1bf + (16 + ln)*32 + quad*8);
    bf16x8 bf0 = __builtin_bit_cast(bf16x8, bw0);
    bf16x8 bf1 = __builtin_bit_cast(bf16x8, bw1);

    float K1 = ws[2];
    float B1_0 = ws[OFF_B1 + ln];
    float B1_1 = (ln < 4) ? ws[OFF_B1 + 16 + ln] : 0.0f;
    __syncthreads();

    for (int i = 0; i < 9; ++i){
        int mt = 9*wv + i;
        int m = mt*16 + ln;
        int p = m >> 2, crn = m & 3;
        int ph_ = p / 12, pw_ = p - 12*ph_;
        int oh = 2*ph_ + (crn >> 1), ow = 2*pw_ + (crn & 1);
        int base = oh*28 + ow;
        int pp = mt*4 + quad;

        floatx4 z = (floatx4){0.f,0.f,0.f,0.f};
        floatx4 a0i[2], a1i[2];
        #pragma unroll
        for (int img = 0; img < 2; ++img){
            uintx4 pv;
            pv[0] = ximp[img][base + o0];
            pv[1] = ximp[img][base + o1];
            pv[2] = ximp[img][base + o2];
            pv[3] = ximp[img][base + o3];
            bf16x8 af = __builtin_bit_cast(bf16x8, pv);
            a0i[img] = __builtin_amdgcn_mfma_f32_16x16x32_bf16(af, bf0, z, 0, 0, 0);
            a1i[img] = __builtin_amdgcn_mfma_f32_16x16x32_bf16(af, bf1, z, 0, 0, 0);
        }

        #pragma unroll
        for (int img = 0; img < 2; ++img){
            {
                float y0 = fmaf(a0i[img][0], K1, B1_0), y1 = fmaf(a0i[img][1], K1, B1_0);
                float y2 = fmaf(a0i[img][2], K1, B1_0), y3 = fmaf(a0i[img][3], K1, B1_0);
                float mA = fmaxf(fmaxf(y0, y1), y2);
                float mf = fmaxf(fmaxf(mA, y3), 0.0f);
                if (__ballot(mf >= 255.5f)){
                    // exact mod-256 wrap path (rare)
                    unsigned int q0 = ((unsigned int)rintf(fmaxf(y0,0.f))) & 255u;
                    unsigned int q1 = ((unsigned int)rintf(fmaxf(y1,0.f))) & 255u;
                    unsigned int qq2 = ((unsigned int)rintf(fmaxf(y2,0.f))) & 255u;
                    unsigned int q3 = ((unsigned int)rintf(fmaxf(y3,0.f))) & 255u;
                    unsigned int h0 = q0 > q1 ? q0 : q1;
                    unsigned int h1 = qq2 > q3 ? qq2 : q3;
                    mf = (float)(h0 > h1 ? h0 : h1);
                } else {
                    mf = rintf(mf);
                }
                xs[img][pp*XSTR + ln] = bfbits(mf);
            }
            if (ln < 4){
                float y0 = fmaf(a1i[img][0], K1, B1_1), y1 = fmaf(a1i[img][1], K1, B1_1);
                float y2 = fmaf(a1i[img][2], K1, B1_1), y3 = fmaf(a1i[img][3], K1, B1_1);
                float mA = fmaxf(fmaxf(y0, y1), y2);
                float mf = fmaxf(fmaxf(mA, y3), 0.0f);
                if (__ballot(mf >= 255.5f)){
                    unsigned int q0 = ((unsigned int)rintf(fmaxf(y0,0.f))) & 255u;
                    unsigned int q1 = ((unsigned int)rintf(fmaxf(y1,0.f))) & 255u;
                    unsigned int qq2 = ((unsigned int)rintf(fmaxf(y2,0.f))) & 255u;
                    unsigned int q3 = ((unsigned int)rintf(fmaxf(y3,0.f))) & 255u;
                    unsigned int h0 = q0 > q1 ? q0 : q1;
                    unsigned int h1 = qq2 > q3 ? qq2 : q3;
                    mf = (float)(h0 > h1 ? h0 : h1);
                } else {
                    mf = rintf(mf);
                }
                xs[img][pp*XSTR + 16 + ln] = bfbits(mf);
            }
        }
    }
    __syncthreads();

    // ---------------- conv2 phase: wave owns 1mt x 4nt, both images ----------------
    int mtw = wv;   // wave's single m-tile
    int abase = (24*mtw + (ln>>3)*12 + (ln&7)) * XSTR;
    int aoff[20];
    #pragma unroll
    for (int c = 0; c < 20; ++c){
        int tap, inner;
        if (c < 13){ tap = 2*c + (quad>>1); inner = (quad&1)*8; }
        else       { tap = 4*(c-13) + quad; inner = 16; }
        int pt = 0;   // invalid taps -> pixel 0 (weights are zero there)
        if (tap < 25){ int kh = tap/5, kw = tap-5*kh; pt = kh*12 + kw; }
        aoff[c] = pt*XSTR + inner;
    }

    float sc2d = ws[0];
    const ushort_t* bsrcs = w2bt + (size_t)ln*32 + quad*8;   // + nt*512 + c*2048

    floatx4 acc[2][4];   // [img][nt]
    #pragma unroll
    for (int g = 0; g < 2; ++g)
        #pragma unroll
        for (int ni = 0; ni < 4; ++ni) acc[g][ni] = (floatx4){0.f,0.f,0.f,0.f};

    #pragma unroll
    for (int c = 0; c < 20; ++c){
        bf16x8 bb[4];
        #pragma unroll
        for (int ni = 0; ni < 4; ++ni)
            bb[ni] = __builtin_bit_cast(bf16x8,
                        *(const ushort8*)(bsrcs + ni*512 + c*2048));
        #pragma unroll
        for (int img = 0; img < 2; ++img){
            ushort8 aw = *(const ushort8*)(xs[img] + abase + aoff[c]);
            bf16x8 a = __builtin_bit_cast(bf16x8, aw);
            #pragma unroll
            for (int ni = 0; ni < 4; ++ni)
                acc[img][ni] = __builtin_amdgcn_mfma_f32_16x16x32_bf16(a, bb[ni], acc[img][ni], 0, 0, 0);
        }
    }

    #pragma unroll
    for (int img = 0; img < 2; ++img){
        int b = b0 + img;
        int bg = b >> 4, brow = b & 15;
        #pragma unroll
        for (int ni = 0; ni < 4; ++ni){
            int co = ni*16 + ln;
            float bias2d = (co < 50) ? ws[OFF_B2 + co] : 0.0f;
            {
                int mt = mtw;
                float y0 = fmaf(acc[img][ni][0], sc2d, bias2d);
                float y1 = fmaf(acc[img][ni][1], sc2d, bias2d);
                float y2 = fmaf(acc[img][ni][2], sc2d, bias2d);
                float y3 = fmaf(acc[img][ni][3], sc2d, bias2d);
                float f0 = fmaxf(fmaxf(y0, y1), 0.0f);
                float f1 = fmaxf(fmaxf(y2, y3), 0.0f);
                float g0 = __shfl_xor(f0, 32);
                float g1 = __shfl_xor(f1, 32);
                float v0f = fmaxf(f0, g0), v1f = fmaxf(f1, g1);
                if (__ballot(fmaxf(v0f, v1f) >= 255.5f)){
                    // exact mod-256 wrap path (rare); wave-uniform so both shfl partners enter
                    unsigned int q0 = ((unsigned int)rintf(fmaxf(y0,0.f))) & 255u;
                    unsigned int q1 = ((unsigned int)rintf(fmaxf(y1,0.f))) & 255u;
                    unsigned int qq2 = ((unsigned int)rintf(fmaxf(y2,0.f))) & 255u;
                    unsigned int q3 = ((unsigned int)rintf(fmaxf(y3,0.f))) & 255u;
                    unsigned int h0 = q0 > q1 ? q0 : q1;
                    unsigned int h1 = qq2 > q3 ? qq2 : q3;
                    unsigned int p0 = (unsigned int)__shfl_xor((int)h0, 32);
                    unsigned int p1 = (unsigned int)__shfl_xor((int)h1, 32);
                    v0f = (float)(h0 > p0 ? h0 : p0);
                    v1f = (float)(h1 > p1 ? h1 : p1);
                } else {
                    v0f = rintf(v0f); v1f = rintf(v1f);
                }
                if (quad < 2 && co < 50){
                    int k0 = co*16 + mt*4 + quad*2;           // flat fc1 K index (even)
                    size_t off = ((size_t)bg*25 + (k0 >> 5))*512 + brow*32 + (k0 & 31);
                    q2bf[off]     = bfbits(v0f);
                    q2bf[off + 1] = bfbits(v1f);
                }
            }
        }
    }
}

// Fused fc1+fc2+log_softmax (tiled coalesced layouts): block = 16 batch rows x all 512
// cols, 512 threads = 8 waves x 4 n-tiles, grid B/16 = 256. A-fragment: q2t[gi][c][ln][32]
// dense 1KB/wave/c; B-fragment: w3t[nt][c][ln][32] dense. Depth-1 prefetch. q3 quantized
// in-register (bit-identical); fc2 butterfly + LDS reduce + per-row log_softmax.
__global__ __launch_bounds__(512) void k_fc12(const ushort_t* q2t, const ushort_t* w3t,
                                              const float* ws, const float* w2,
                                              const float* b2, float* out, int B){
    __shared__ float red[8*16*10];    // [wv][row16][c10]
    int tid = threadIdx.x;
    int lane = tid & 63, wv = tid >> 6;    // wv in [0,8)
    int ln = lane & 15, quad = lane >> 4;
    int gi = blockIdx.x;
    int b0 = gi * 16;

    const ushort_t* asrc = q2t + (size_t)gi*25*512 + ln*32 + quad*8;
    const ushort_t* bsrc = w3t + (size_t)(wv*4)*25*512 + ln*32 + quad*8;

    floatx4 acc[4];
    #pragma unroll
    for (int t = 0; t < 4; ++t) acc[t] = (floatx4){0.f,0.f,0.f,0.f};

    ushort8 aw = *(const ushort8*)(asrc);
    ushort8 bw[4];
    #pragma unroll
    for (int t = 0; t < 4; ++t) bw[t] = *(const ushort8*)(bsrc + t*12800);

    #pragma unroll
    for (int c = 0; c < 25; ++c){
        ushort8 aN; ushort8 bN[4];
        if (c < 24){
            aN = *(const ushort8*)(asrc + (c+1)*512);
            #pragma unroll
            for (int t = 0; t < 4; ++t)
                bN[t] = *(const ushort8*)(bsrc + t*12800 + (c+1)*512);
        }
        #pragma unroll
        for (int t = 0; t < 4; ++t)
            acc[t] = __builtin_amdgcn_mfma_f32_16x16x32_bf16(
                         __builtin_bit_cast(bf16x8, aw), __builtin_bit_cast(bf16x8, bw[t]),
                         acc[t], 0, 0, 0);
        aw = aN;
        #pragma unroll
        for (int t = 0; t < 4; ++t) bw[t] = bN[t];
    }

    // quantize q3 in-register (bit-identical (uint)rintf&255 then S_N3*q)
    float sc3d = ws[1];
    float xf[4][4];
    #pragma unroll
    for (int t = 0; t < 4; ++t){
        int col = wv*64 + t*16 + ln;
        float bias = (col < 500) ? ws[OFF_B3 + col] : 0.0f;
        #pragma unroll
        for (int r = 0; r < 4; ++r){
            float y = fmaxf(fmaf(acc[t][r], sc3d, bias), 0.0f);
            unsigned int q = ((unsigned int)rintf(y)) & 255u;
            xf[r][t] = (col < 500) ? S_N3 * (float)q : 0.0f;
        }
    }

    // fc2: per class c, partial over this lane's 4 cols, butterfly over the 16-lane
    // group (masks 1,2,4,8 stay within quad group), wave-leader writes to LDS.
    #pragma unroll
    for (int c = 0; c < 10; ++c){
        float p[4] = {0.f, 0.f, 0.f, 0.f};
        #pragma unroll
        for (int t = 0; t < 4; ++t){
            int col = wv*64 + t*16 + ln;
            float w = (col < 500) ? w2[c*500 + col] : 0.0f;
            #pragma unroll
            for (int r = 0; r < 4; ++r) p[r] = fmaf(xf[r][t], w, p[r]);
        }
        #pragma unroll
        for (int m = 1; m <= 8; m <<= 1)
            #pragma unroll
            for (int r = 0; r < 4; ++r) p[r] += __shfl_xor(p[r], m);
        if (ln == 0){
            #pragma unroll
            for (int r = 0; r < 4; ++r)
                red[(wv*16 + quad*4 + r)*10 + c] = p[r];
        }
    }
    __syncthreads();

    if (tid < 16){
        int row = tid;
        float lg[10], mx = -INFINITY;
        #pragma unroll
        for (int c = 0; c < 10; ++c){
            float s = b2[c];
            #pragma unroll
            for (int w = 0; w < 8; ++w) s += red[(w*16 + row)*10 + c];
            lg[c] = s; mx = fmaxf(mx, s);
        }
        float sum = 0.0f;
        #pragma unroll
        for (int c = 0; c < 10; ++c) sum += expf(lg[c] - mx);
        float ls = logf(sum);
        #pragma unroll
        for (int c = 0; c < 10; ++c)
            out[(size_t)(b0 + row)*10 + c] = lg[c] - mx - ls;
    }
}

extern "C" void kernel_launch(void* const* d_in, const int* in_sizes, int n_in,
                              void* d_out, int out_size, void* d_ws, size_t ws_size,
                              hipStream_t stream){
    const float* x   = (const float*)d_in[0];
    const float* c1w = (const float*)d_in[1];
    const float* c1b = (const float*)d_in[2];
    const float* c2w = (const float*)d_in[3];
    const float* c2b = (const float*)d_in[4];
    const float* f1w = (const float*)d_in[5];
    const float* f1b = (const float*)d_in[6];
    const float* f2w = (const float*)d_in[7];
    const float* f2b = (const float*)d_in[8];
    int B = in_sizes[0] / 784;

    float* ws = (float*)d_ws;
    float* pmn = ws + OFF_PMN;
    float* pmx = ws + OFF_PMX;
    ushort_t* w1bf = (ushort_t*)((char*)d_ws + W1BF_BYTE);
    ushort_t* w2bf = (ushort_t*)((char*)d_ws + W2BF_BYTE);
    ushort_t* w3bf = (ushort_t*)((char*)d_ws + W3BF_BYTE);
    ushort_t* q2bf = (ushort_t*)((char*)d_ws + Q2_BYTE);
    float* out = (float*)d_out;

    k_minmax<<<72, TPB, 0, stream>>>(c1w, c1b, c2w, c2b, f1w, f1b, pmn, pmx);
    k_make_eff<<<(N_EFF + TPB - 1)/TPB, TPB, 0, stream>>>(c1w, c1b, c2w, c2b, f1w, f1b, pmn, pmx, ws, w1bf, w2bf, w3bf);
    k_conv12<<<B/2, TPB, 0, stream>>>(x, w1bf, w2bf, ws, q2bf, B);
    k_fc12<<<B/16, 512, 0, stream>>>(q2bf, w3bf, ws, f2w, f2b, out, B);
}

// Round 15
// 141.026 us; speedup vs baseline: 1.1438x; 1.1438x over previous
//
#include <hip/hip_runtime.h>
#include <cmath>

#define TPB 256
typedef float floatx4 __attribute__((ext_vector_type(4)));
typedef __bf16 bf16x8 __attribute__((ext_vector_type(8)));
typedef unsigned short ushort8 __attribute__((ext_vector_type(8)));
typedef unsigned int uintx4 __attribute__((ext_vector_type(4)));
typedef unsigned short ushort_t;

// ---------- workspace layout (float units) ----------
#define OFF_PMN 16
#define OFF_PMX 96
#define OFF_B1 520       // 20  f32  (pre-divided by S_N1)
#define OFF_B2 544       // 50  f32  (pre-divided by S_N2)
#define OFF_B3 600       // 500 f32  (pre-divided by S_N3)
#define W1BF_BYTE 6144       // [32][32] u16 int weights (conv1), pair-slot packed (TAPOF)
#define W2BF_BYTE 8192       // [20 chunks][64 co][32 k] u16 int weights (conv2), 81920 B
#define W3BF_BYTE 131072     // w3t: [nt32][c25][ln16][k32] u16 (fc1), 819200 B
#define Q2_BYTE  29360128ULL // q2t: [B/16][c25][ln16][k32] bf16 (6.6 MB)

#define S_X1 (3.5f/255.0f)
#define ZP_X1 36.0f
#define S_N1 (6.0f/255.0f)
#define S_N2 (8.0f/255.0f)
#define S_N3 (10.0f/255.0f)

// LDS pixel stride 24 u16 (R13-verified): 16-lane b128 group -> 2-way bank alias (free).
#define XSTR 24
// R27: FOUR images per block (ILP is the only lever that has ever moved conv12:
// R8's 2-img gave -21%; occupancy/instruction/LDS-traffic levers all null or negative).
#define IMGS 4

// conv1 K-slot -> tap map (pair packing). Slot k (0..31): quad=k>>3, j=k&7.
__device__ const signed char TAPOF[32] = {
     0,  1,  2,  3,  4, -1,  5,  6,     // quad0: (0,0..4),(0,5)g,(1,0),(1,1)
     7,  8,  9, -1, 10, 11, 12, 13,     // quad1: (1,2..4),(1,5)g,(2,0..3)
    14, -1, 15, 16, 17, 18, 19, -1,     // quad2: (2,4),(2,5)g,(3,0..4),(3,5)g
    20, 21, 22, 23, 24, -1, -1, -1      // quad3: (4,0..4),(4,5)g,g,g
};
// pair-index read offsets per quad (pixel index of each pair's low element)
__device__ const int OFFP[4][4] = {
    {0, 2, 4, 28},          // (0,0),(0,2),(0,4),(1,0)
    {30, 32, 56, 58},       // (1,2),(1,4),(2,0),(2,2)
    {60, 84, 86, 88},       // (2,4),(3,0),(3,2),(3,4)
    {112, 114, 116, 112}    // (4,0),(4,2),(4,4),dup(zero wt)
};

__device__ inline float qclip(float x, float s, float zp){
    return rintf(fminf(fmaxf(zp + x / s, 0.0f), 255.0f));
}
// exact bf16 bits for integer-valued floats |v| < 256
__device__ inline ushort_t bfbits(float v){
    return (ushort_t)(__float_as_uint(v) >> 16);
}

// per-block min/max partials; block->tensor map: 0:c1w 1:c1b 2-5:c2w 6:c2b 7-70:f1w 71:f1b
__global__ __launch_bounds__(TPB) void k_minmax(
        const float* c1w, const float* c1b, const float* c2w, const float* c2b,
        const float* f1w, const float* f1b, float* pmn, float* pmx){
    __shared__ float smn[TPB], smx[TPB];
    int bb = blockIdx.x, tid = threadIdx.x;
    const float* src; int n, sub, nsub;
    if      (bb == 0){ src=c1w; n=500;    sub=0;     nsub=1;  }
    else if (bb == 1){ src=c1b; n=20;     sub=0;     nsub=1;  }
    else if (bb <  6){ src=c2w; n=25000;  sub=bb-2;  nsub=4;  }
    else if (bb == 6){ src=c2b; n=50;     sub=0;     nsub=1;  }
    else if (bb < 71){ src=f1w; n=400000; sub=bb-7;  nsub=64; }
    else             { src=f1b; n=500;    sub=0;     nsub=1;  }
    float mn = INFINITY, mx = -INFINITY;
    for (int i = sub*TPB + tid; i < n; i += nsub*TPB){
        float v = src[i]; mn = fminf(mn, v); mx = fmaxf(mx, v);
    }
    smn[tid] = mn; smx[tid] = mx; __syncthreads();
    for (int s = TPB/2; s > 0; s >>= 1){
        if (tid < s){
            smn[tid] = fminf(smn[tid], smn[tid+s]);
            smx[tid] = fmaxf(smx[tid], smx[tid+s]);
        }
        __syncthreads();
    }
    if (tid == 0){ pmn[bb] = smn[0]; pmx[bb] = smx[0]; }
}

// w2bt chunk packing (20 chunks of K=32):
//   main c in 0..12:   oct q -> tap = 2c + (q>>1), ci = (q&1)*8 + jj   (tap 25 -> zero)
//   residue c in 13..19: oct q -> tap = 4(c-13) + q, ci = 16 + jj (jj<4; jj>=4 -> zero)
#define N_EFF 452157
__global__ __launch_bounds__(TPB) void k_make_eff(
        const float* c1w, const float* c1b, const float* c2w, const float* c2b,
        const float* f1w, const float* f1b, const float* pmn, const float* pmx,
        float* ws, ushort_t* w1bf, ushort_t* w2bf, ushort_t* w3bf){
    __shared__ float sS[6], sZ[6];
    int tid = threadIdx.x;
    int wv = tid >> 6, lane = tid & 63;
    const int starts[6] = {0,1,2,6,7,71};
    const int counts[6] = {1,1,4,1,64,1};
    #pragma unroll
    for (int rep = 0; rep < 2; ++rep){
        int t = wv + rep*4;
        if (t < 6){
            float mn = INFINITY, mx = -INFINITY;
            if (lane < counts[t]){ mn = pmn[starts[t]+lane]; mx = pmx[starts[t]+lane]; }
            #pragma unroll
            for (int off = 32; off > 0; off >>= 1){
                mn = fminf(mn, __shfl_xor(mn, off));
                mx = fmaxf(mx, __shfl_xor(mx, off));
            }
            if (lane == 0){
                float s = (mx - mn) / 255.0f;
                sS[t] = s;
                sZ[t] = truncf(fminf(fmaxf(0.0f - mn / s, 0.0f), 255.0f));
            }
        }
    }
    __syncthreads();

    int i = blockIdx.x * TPB + tid;
    if (i >= N_EFF) return;
    if (i < 1024){                   // w1bf: [n(32)][k(32)] pair-slot packed per TAPOF
        int n = i >> 5, k = i & 31;
        int tap = (int)TAPOF[k];
        float v = 0.0f;
        if (n < 20 && tap >= 0) v = qclip(c1w[n*25 + tap], sS[0], sZ[0]) - sZ[0];
        w1bf[i] = bfbits(v);
    } else if (i < 1044){            // b1 pre-divided by S_N1
        int j = i - 1024;
        ws[OFF_B1 + j] = (sS[1] * (qclip(c1b[j], sS[1], sZ[1]) + sZ[1])) / S_N1;
    } else if (i < 42004){           // w2bt chunk-packed
        int j = i - 1044;
        int c = j >> 11, r = j & 2047, co = r >> 5, k = r & 31;
        int q = k >> 3, jj = k & 7;
        int tap, ci; bool valid;
        if (c < 13){ tap = 2*c + (q>>1); ci = (q&1)*8 + jj; valid = (tap < 25); }
        else       { tap = 4*(c-13) + q; ci = 16 + jj;      valid = (tap < 25) && (jj < 4); }
        valid = valid && (co < 50);
        float v = 0.0f;
        if (valid) v = qclip(c2w[(co*20 + ci)*25 + tap], sS[2], sZ[2]) - sZ[2];
        w2bf[j] = bfbits(v);
    } else if (i < 42054){           // b2 pre-divided by S_N2
        int j = i - 42004;
        ws[OFF_B2 + j] = (sS[3] * (qclip(c2b[j], sS[3], sZ[3]) + sZ[3])) / S_N2;
    } else if (i < 451654){          // w3t: tiled [nt(32)][c(25)][ln(16)][k(32)]
        int j = i - 42054;
        int n = j / 800, k = j - 800*n;
        float v = 0.0f;
        if (n < 500) v = qclip(f1w[n*800 + k], sS[4], sZ[4]) - sZ[4];
        w3bf[(((n>>4)*25 + (k>>5))*16 + (n&15))*32 + (k&31)] = bfbits(v);
    } else if (i < 452154){          // b3 pre-divided by S_N3
        int j = i - 451654;
        ws[OFF_B3 + j] = (sS[5] * (qclip(f1b[j], sS[5], sZ[5]) + sZ[5])) / S_N3;
    } else if (i == 452154){
        ws[0] = (S_N1 * sS[2]) / S_N2;   // conv2 combined scale, pre-divided
    } else if (i == 452155){
        ws[1] = (S_N2 * sS[4]) / S_N3;   // fc1 combined scale, pre-divided
    } else {
        ws[2] = (S_X1 * sS[0]) / S_N1;   // conv1 combined scale, pre-divided
    }
}

// Fused conv1+conv2, FOUR images per block (grid B/4). R27: img dimension 2 -> 4 on the
// R13-verified structure (2mt x 2nt conv2 mapping, XSTR=24). Per c-step a wave runs 16
// independent MFMAs from 8 A-LDS-reads + 2 B-loads (B serves 4 images). LDS 40.2 KB ->
// 4 blocks/CU (occupancy proven non-binding in R13). Math bit-identical.
__global__ __launch_bounds__(TPB, 4) void k_conv12(const float* x, const ushort_t* w1bf,
                                                   const ushort_t* w2bt, const float* ws,
                                                   ushort_t* q2bf, int B){
    __shared__ __align__(16) ushort_t xs[IMGS][144*XSTR];    // conv2 input per image
    __shared__ __align__(16) unsigned int ximp[IMGS][784];   // pair-packed quantized images
    int b0 = blockIdx.x * IMGS, tid = threadIdx.x;
    int lane = tid & 63, wv = tid >> 6;
    int ln = lane & 15, quad = lane >> 4;

    // zero xs pad columns 20-23 once
    for (int i = tid; i < 144*IMGS; i += TPB){
        int img = i / 144;
        int p = i - img*144;
        *(unsigned int*)(xs[img] + p*XSTR + 20) = 0u;
        *(unsigned int*)(xs[img] + p*XSTR + 22) = 0u;
    }

    // ---------------- conv1 phase ----------------
    #pragma unroll
    for (int img = 0; img < IMGS; ++img){
        const float* xb = x + (size_t)(b0 + img) * 784;
        if (tid < 196){
            floatx4 v = *(const floatx4*)(xb + tid*4);
            float x5 = (tid < 195) ? xb[tid*4 + 4] : 0.0f;
            ushort_t bq[5];
            #pragma unroll
            for (int j = 0; j < 4; ++j)
                bq[j] = bfbits(rintf(fminf(fmaxf(ZP_X1 + v[j] / S_X1, 0.0f), 255.0f)) - ZP_X1);
            bq[4] = bfbits(rintf(fminf(fmaxf(ZP_X1 + x5 / S_X1, 0.0f), 255.0f)) - ZP_X1);
            uintx4 P;
            #pragma unroll
            for (int j = 0; j < 4; ++j)
                P[j] = (unsigned int)bq[j] | ((unsigned int)bq[j+1] << 16);
            *(uintx4*)(&ximp[img][tid*4]) = P;
        }
    }

    int o0 = OFFP[quad][0], o1 = OFFP[quad][1], o2 = OFFP[quad][2], o3 = OFFP[quad][3];

    ushort8 bw0 = *(const ushort8*)(w1bf + ln*32 + quad*8);
    ushort8 bw1 = *(const ushort8*)(w1bf + (16 + ln)*32 + quad*8);
    bf16x8 bf0 = __builtin_bit_cast(bf16x8, bw0);
    bf16x8 bf1 = __builtin_bit_cast(bf16x8, bw1);

    float K1 = ws[2];
    float B1_0 = ws[OFF_B1 + ln];
    float B1_1 = (ln < 4) ? ws[OFF_B1 + 16 + ln] : 0.0f;
    __syncthreads();

    for (int i = 0; i < 9; ++i){
        int mt = 9*wv + i;
        int m = mt*16 + ln;
        int p = m >> 2, crn = m & 3;
        int ph_ = p / 12, pw_ = p - 12*ph_;
        int oh = 2*ph_ + (crn >> 1), ow = 2*pw_ + (crn & 1);
        int base = oh*28 + ow;
        int pp = mt*4 + quad;

        floatx4 z = (floatx4){0.f,0.f,0.f,0.f};
        floatx4 a0i[IMGS], a1i[IMGS];
        #pragma unroll
        for (int img = 0; img < IMGS; ++img){
            uintx4 pv;
            pv[0] = ximp[img][base + o0];
            pv[1] = ximp[img][base + o1];
            pv[2] = ximp[img][base + o2];
            pv[3] = ximp[img][base + o3];
            bf16x8 af = __builtin_bit_cast(bf16x8, pv);
            a0i[img] = __builtin_amdgcn_mfma_f32_16x16x32_bf16(af, bf0, z, 0, 0, 0);
            a1i[img] = __builtin_amdgcn_mfma_f32_16x16x32_bf16(af, bf1, z, 0, 0, 0);
        }

        #pragma unroll
        for (int img = 0; img < IMGS; ++img){
            {
                float y0 = fmaf(a0i[img][0], K1, B1_0), y1 = fmaf(a0i[img][1], K1, B1_0);
                float y2 = fmaf(a0i[img][2], K1, B1_0), y3 = fmaf(a0i[img][3], K1, B1_0);
                float mA = fmaxf(fmaxf(y0, y1), y2);
                float mf = fmaxf(fmaxf(mA, y3), 0.0f);
                if (__ballot(mf >= 255.5f)){
                    // exact mod-256 wrap path (rare)
                    unsigned int q0 = ((unsigned int)rintf(fmaxf(y0,0.f))) & 255u;
                    unsigned int q1 = ((unsigned int)rintf(fmaxf(y1,0.f))) & 255u;
                    unsigned int qq2 = ((unsigned int)rintf(fmaxf(y2,0.f))) & 255u;
                    unsigned int q3 = ((unsigned int)rintf(fmaxf(y3,0.f))) & 255u;
                    unsigned int h0 = q0 > q1 ? q0 : q1;
                    unsigned int h1 = qq2 > q3 ? qq2 : q3;
                    mf = (float)(h0 > h1 ? h0 : h1);
                } else {
                    mf = rintf(mf);
                }
                xs[img][pp*XSTR + ln] = bfbits(mf);
            }
            if (ln < 4){
                float y0 = fmaf(a1i[img][0], K1, B1_1), y1 = fmaf(a1i[img][1], K1, B1_1);
                float y2 = fmaf(a1i[img][2], K1, B1_1), y3 = fmaf(a1i[img][3], K1, B1_1);
                float mA = fmaxf(fmaxf(y0, y1), y2);
                float mf = fmaxf(fmaxf(mA, y3), 0.0f);
                if (__ballot(mf >= 255.5f)){
                    unsigned int q0 = ((unsigned int)rintf(fmaxf(y0,0.f))) & 255u;
                    unsigned int q1 = ((unsigned int)rintf(fmaxf(y1,0.f))) & 255u;
                    unsigned int qq2 = ((unsigned int)rintf(fmaxf(y2,0.f))) & 255u;
                    unsigned int q3 = ((unsigned int)rintf(fmaxf(y3,0.f))) & 255u;
                    unsigned int h0 = q0 > q1 ? q0 : q1;
                    unsigned int h1 = qq2 > q3 ? qq2 : q3;
                    mf = (float)(h0 > h1 ? h0 : h1);
                } else {
                    mf = rintf(mf);
                }
                xs[img][pp*XSTR + 16 + ln] = bfbits(mf);
            }
        }
    }
    __syncthreads();

    // ---------------- conv2 phase: wave owns 2mt x 2nt, all images ----------------
    int mt0 = (wv & 1) * 2;
    int nt0 = (wv >> 1) * 2;
    int abase[2];
    #pragma unroll
    for (int mi = 0; mi < 2; ++mi)
        abase[mi] = (24*(mt0+mi) + (ln>>3)*12 + (ln&7)) * XSTR;
    int aoff[20];
    #pragma unroll
    for (int c = 0; c < 20; ++c){
        int tap, inner;
        if (c < 13){ tap = 2*c + (quad>>1); inner = (quad&1)*8; }
        else       { tap = 4*(c-13) + quad; inner = 16; }
        int pt = 0;   // invalid taps -> pixel 0 (weights are zero there)
        if (tap < 25){ int kh = tap/5, kw = tap-5*kh; pt = kh*12 + kw; }
        aoff[c] = pt*XSTR + inner;
    }

    float sc2d = ws[0];
    const ushort_t* bsrc0 = w2bt + (size_t)(nt0*16 + ln)*32 + quad*8;
    const ushort_t* bsrc1 = bsrc0 + 16*32;

    floatx4 acc[IMGS][2][2];   // [img][mi][ni]
    #pragma unroll
    for (int g = 0; g < IMGS; ++g)
        #pragma unroll
        for (int mi = 0; mi < 2; ++mi)
            #pragma unroll
            for (int ni = 0; ni < 2; ++ni) acc[g][mi][ni] = (floatx4){0.f,0.f,0.f,0.f};

    #pragma unroll
    for (int c = 0; c < 20; ++c){
        ushort8 b0w = *(const ushort8*)(bsrc0 + c*2048);
        ushort8 b1w = *(const ushort8*)(bsrc1 + c*2048);
        bf16x8 bb0 = __builtin_bit_cast(bf16x8, b0w);
        bf16x8 bb1 = __builtin_bit_cast(bf16x8, b1w);
        #pragma unroll
        for (int img = 0; img < IMGS; ++img){
            ushort8 a0w = *(const ushort8*)(xs[img] + abase[0] + aoff[c]);
            ushort8 a1w = *(const ushort8*)(xs[img] + abase[1] + aoff[c]);
            bf16x8 a0 = __builtin_bit_cast(bf16x8, a0w);
            bf16x8 a1 = __builtin_bit_cast(bf16x8, a1w);
            acc[img][0][0] = __builtin_amdgcn_mfma_f32_16x16x32_bf16(a0, bb0, acc[img][0][0], 0, 0, 0);
            acc[img][0][1] = __builtin_amdgcn_mfma_f32_16x16x32_bf16(a0, bb1, acc[img][0][1], 0, 0, 0);
            acc[img][1][0] = __builtin_amdgcn_mfma_f32_16x16x32_bf16(a1, bb0, acc[img][1][0], 0, 0, 0);
            acc[img][1][1] = __builtin_amdgcn_mfma_f32_16x16x32_bf16(a1, bb1, acc[img][1][1], 0, 0, 0);
        }
    }

    #pragma unroll
    for (int img = 0; img < IMGS; ++img){
        int b = b0 + img;
        int bg = b >> 4, brow = b & 15;
        #pragma unroll
        for (int ni = 0; ni < 2; ++ni){
            int co = (nt0 + ni)*16 + ln;
            float bias2d = (co < 50) ? ws[OFF_B2 + co] : 0.0f;
            #pragma unroll
            for (int mi = 0; mi < 2; ++mi){
                int mt = mt0 + mi;
                float y0 = fmaf(acc[img][mi][ni][0], sc2d, bias2d);
                float y1 = fmaf(acc[img][mi][ni][1], sc2d, bias2d);
                float y2 = fmaf(acc[img][mi][ni][2], sc2d, bias2d);
                float y3 = fmaf(acc[img][mi][ni][3], sc2d, bias2d);
                float f0 = fmaxf(fmaxf(y0, y1), 0.0f);
                float f1 = fmaxf(fmaxf(y2, y3), 0.0f);
                float g0 = __shfl_xor(f0, 32);
                float g1 = __shfl_xor(f1, 32);
                float v0f = fmaxf(f0, g0), v1f = fmaxf(f1, g1);
                if (__ballot(fmaxf(v0f, v1f) >= 255.5f)){
                    // exact mod-256 wrap path (rare); wave-uniform so both shfl partners enter
                    unsigned int q0 = ((unsigned int)rintf(fmaxf(y0,0.f))) & 255u;
                    unsigned int q1 = ((unsigned int)rintf(fmaxf(y1,0.f))) & 255u;
                    unsigned int qq2 = ((unsigned int)rintf(fmaxf(y2,0.f))) & 255u;
                    unsigned int q3 = ((unsigned int)rintf(fmaxf(y3,0.f))) & 255u;
                    unsigned int h0 = q0 > q1 ? q0 : q1;
                    unsigned int h1 = qq2 > q3 ? qq2 : q3;
                    unsigned int p0 = (unsigned int)__shfl_xor((int)h0, 32);
                    unsigned int p1 = (unsigned int)__shfl_xor((int)h1, 32);
                    v0f = (float)(h0 > p0 ? h0 : p0);
                    v1f = (float)(h1 > p1 ? h1 : p1);
                } else {
                    v0f = rintf(v0f); v1f = rintf(v1f);
                }
                if (quad < 2 && co < 50){
                    int k0 = co*16 + mt*4 + quad*2;           // flat fc1 K index (even)
                    size_t off = ((size_t)bg*25 + (k0 >> 5))*512 + brow*32 + (k0 & 31);
                    q2bf[off]     = bfbits(v0f);
                    q2bf[off + 1] = bfbits(v1f);
                }
            }
        }
    }
}

// Fused fc1+fc2+log_softmax (tiled coalesced layouts): block = 16 batch rows x all 512
// cols, 512 threads = 8 waves x 4 n-tiles, grid B/16 = 256. A-fragment: q2t[gi][c][ln][32]
// dense 1KB/wave/c; B-fragment: w3t[nt][c][ln][32] dense. Depth-1 prefetch. q3 quantized
// in-register (bit-identical); fc2 butterfly + LDS reduce + per-row log_softmax.
__global__ __launch_bounds__(512) void k_fc12(const ushort_t* q2t, const ushort_t* w3t,
                                              const float* ws, const float* w2,
                                              const float* b2, float* out, int B){
    __shared__ float red[8*16*10];    // [wv][row16][c10]
    int tid = threadIdx.x;
    int lane = tid & 63, wv = tid >> 6;    // wv in [0,8)
    int ln = lane & 15, quad = lane >> 4;
    int gi = blockIdx.x;
    int b0 = gi * 16;

    const ushort_t* asrc = q2t + (size_t)gi*25*512 + ln*32 + quad*8;
    const ushort_t* bsrc = w3t + (size_t)(wv*4)*25*512 + ln*32 + quad*8;

    floatx4 acc[4];
    #pragma unroll
    for (int t = 0; t < 4; ++t) acc[t] = (floatx4){0.f,0.f,0.f,0.f};

    ushort8 aw = *(const ushort8*)(asrc);
    ushort8 bw[4];
    #pragma unroll
    for (int t = 0; t < 4; ++t) bw[t] = *(const ushort8*)(bsrc + t*12800);

    #pragma unroll
    for (int c = 0; c < 25; ++c){
        ushort8 aN; ushort8 bN[4];
        if (c < 24){
            aN = *(const ushort8*)(asrc + (c+1)*512);
            #pragma unroll
            for (int t = 0; t < 4; ++t)
                bN[t] = *(const ushort8*)(bsrc + t*12800 + (c+1)*512);
        }
        #pragma unroll
        for (int t = 0; t < 4; ++t)
            acc[t] = __builtin_amdgcn_mfma_f32_16x16x32_bf16(
                         __builtin_bit_cast(bf16x8, aw), __builtin_bit_cast(bf16x8, bw[t]),
                         acc[t], 0, 0, 0);
        aw = aN;
        #pragma unroll
        for (int t = 0; t < 4; ++t) bw[t] = bN[t];
    }

    // quantize q3 in-register (bit-identical (uint)rintf&255 then S_N3*q)
    float sc3d = ws[1];
    float xf[4][4];
    #pragma unroll
    for (int t = 0; t < 4; ++t){
        int col = wv*64 + t*16 + ln;
        float bias = (col < 500) ? ws[OFF_B3 + col] : 0.0f;
        #pragma unroll
        for (int r = 0; r < 4; ++r){
            float y = fmaxf(fmaf(acc[t][r], sc3d, bias), 0.0f);
            unsigned int q = ((unsigned int)rintf(y)) & 255u;
            xf[r][t] = (col < 500) ? S_N3 * (float)q : 0.0f;
        }
    }

    // fc2: per class c, partial over this lane's 4 cols, butterfly over the 16-lane
    // group (masks 1,2,4,8 stay within quad group), wave-leader writes to LDS.
    #pragma unroll
    for (int c = 0; c < 10; ++c){
        float p[4] = {0.f, 0.f, 0.f, 0.f};
        #pragma unroll
        for (int t = 0; t < 4; ++t){
            int col = wv*64 + t*16 + ln;
            float w = (col < 500) ? w2[c*500 + col] : 0.0f;
            #pragma unroll
            for (int r = 0; r < 4; ++r) p[r] = fmaf(xf[r][t], w, p[r]);
        }
        #pragma unroll
        for (int m = 1; m <= 8; m <<= 1)
            #pragma unroll
            for (int r = 0; r < 4; ++r) p[r] += __shfl_xor(p[r], m);
        if (ln == 0){
            #pragma unroll
            for (int r = 0; r < 4; ++r)
                red[(wv*16 + quad*4 + r)*10 + c] = p[r];
        }
    }
    __syncthreads();

    if (tid < 16){
        int row = tid;
        float lg[10], mx = -INFINITY;
        #pragma unroll
        for (int c = 0; c < 10; ++c){
            float s = b2[c];
            #pragma unroll
            for (int w = 0; w < 8; ++w) s += red[(w*16 + row)*10 + c];
            lg[c] = s; mx = fmaxf(mx, s);
        }
        float sum = 0.0f;
        #pragma unroll
        for (int c = 0; c < 10; ++c) sum += expf(lg[c] - mx);
        float ls = logf(sum);
        #pragma unroll
        for (int c = 0; c < 10; ++c)
            out[(size_t)(b0 + row)*10 + c] = lg[c] - mx - ls;
    }
}

extern "C" void kernel_launch(void* const* d_in, const int* in_sizes, int n_in,
                              void* d_out, int out_size, void* d_ws, size_t ws_size,
                              hipStream_t stream){
    const float* x   = (const float*)d_in[0];
    const float* c1w = (const float*)d_in[1];
    const float* c1b = (const float*)d_in[2];
    const float* c2w = (const float*)d_in[3];
    const float* c2b = (const float*)d_in[4];
    const float* f1w = (const float*)d_in[5];
    const float* f1b = (const float*)d_in[6];
    const float* f2w = (const float*)d_in[7];
    const float* f2b = (const float*)d_in[8];
    int B = in_sizes[0] / 784;

    float* ws = (float*)d_ws;
    float* pmn = ws + OFF_PMN;
    float* pmx = ws + OFF_PMX;
    ushort_t* w1bf = (ushort_t*)((char*)d_ws + W1BF_BYTE);
    ushort_t* w2bf = (ushort_t*)((char*)d_ws + W2BF_BYTE);
    ushort_t* w3bf = (ushort_t*)((char*)d_ws + W3BF_BYTE);
    ushort_t* q2bf = (ushort_t*)((char*)d_ws + Q2_BYTE);
    float* out = (float*)d_out;

    k_minmax<<<72, TPB, 0, stream>>>(c1w, c1b, c2w, c2b, f1w, f1b, pmn, pmx);
    k_make_eff<<<(N_EFF + TPB - 1)/TPB, TPB, 0, stream>>>(c1w, c1b, c2w, c2b, f1w, f1b, pmn, pmx, ws, w1bf, w2bf, w3bf);
    k_conv12<<<B/IMGS, TPB, 0, stream>>>(x, w1bf, w2bf, ws, q2bf, B);
    k_fc12<<<B/16, 512, 0, stream>>>(q2bf, w3bf, ws, f2w, f2b, out, B);
}